// Round 15
// baseline (190.663 us; speedup 1.0000x reference)
//
#include <hip/hip_runtime.h>
#include <hip/hip_bf16.h>

// ReasoningMultiHeadAttention: B=4 S=2048 HID=1024 NH=16 DH=64. All I/O fp32.
// prep: 6x W -> bf16 W^T pre-swizzled (wt) ; x -> bf16 xb pre-swizzled (d_out lo)
// gated m97-style (R15): BM=128 dual-B, 256 thr, SINGLE-buffered 48KB LDS ->
//   2 blocks/CU co-resident; simple 2-barrier loop; cross-block overlap hides
//   drains (m114 mechanism). Grid 128x8x2 = 2048 blocks.
// plain8<bf16>: xb @ WvT + bv -> vv ; triple-buffer, 1 BAR/tile, vmcnt(6)
// attn: MFMA per-token cross-head attention (R14)
// plain8<f32>: ar @ WoT + bo -> d_out
// ws: [0:12M wt][12:28M qg][28:44M vv][44:60M ar]; d_out scratch: xb | kg.

typedef __attribute__((ext_vector_type(8))) short short8;
typedef __attribute__((ext_vector_type(4))) short short4v;
typedef __attribute__((ext_vector_type(4))) float f32x4;

#define HID 1024
#define NTOK 8192
#define WT_ELEMS (1024 * 1024)

__device__ __forceinline__ short f2bs(float f) {
  __hip_bfloat16 h = __float2bfloat16(f);
  return *reinterpret_cast<short*>(&h);
}
__device__ __forceinline__ float bs2f(short s) {
  __hip_bfloat16 h;
  *reinterpret_cast<short*>(&h) = s;
  return __bfloat162float(h);
}
__device__ __forceinline__ void gload16(const void* g, void* l) {
  __builtin_amdgcn_global_load_lds(
      (const __attribute__((address_space(1))) void*)g,
      (__attribute__((address_space(3))) void*)l, 16, 0, 0);
}

#define BAR() asm volatile("s_barrier" ::: "memory")
#define VMWAIT(N) asm volatile("s_waitcnt vmcnt(" #N ")" ::: "memory")
#define SCB __builtin_amdgcn_sched_barrier(0)
#define PRIO1 __builtin_amdgcn_s_setprio(1)
#define PRIO0 __builtin_amdgcn_s_setprio(0)
#define MFMA16x16 __builtin_amdgcn_mfma_f32_16x16x32_bf16

// ---------------- prep: W transposes (z<6) + x fp32->bf16 convert ----------
__global__ __launch_bounds__(256) void prep_kernel(
    const float* __restrict__ W0, const float* __restrict__ W1,
    const float* __restrict__ W2, const float* __restrict__ W3,
    const float* __restrict__ W4, const float* __restrict__ W5,
    const float* __restrict__ X, short* __restrict__ WT, short* __restrict__ XB)
{
  __shared__ short sT[64][68];
  const int bid = blockIdx.x, tid = threadIdx.x;
  if (bid < 1536) {
    const int z = bid >> 8, rem = bid & 255;
    const float* W = z == 0 ? W0 : z == 1 ? W1 : z == 2 ? W2 : z == 3 ? W3
                   : z == 4 ? W4 : W5;
    short* OUT = WT + (size_t)z * WT_ELEMS;
    const int k0 = (rem & 15) * 64, n0 = (rem >> 4) * 64;
    #pragma unroll
    for (int i = 0; i < 4; i++) {
      const int li = tid + i * 256;
      const int kr = li >> 4, c4 = (li & 15) << 2;
      const f32x4 wv = *reinterpret_cast<const f32x4*>(&W[(size_t)(k0 + kr) * HID + n0 + c4]);
      short4v s4;
      #pragma unroll
      for (int j = 0; j < 4; j++) s4[j] = f2bs(wv[j]);
      *reinterpret_cast<short4v*>(&sT[kr][c4]) = s4;
    }
    __syncthreads();
    #pragma unroll
    for (int i = 0; i < 4; i++) {
      const int li = tid + i * 256;
      const int nr = li >> 4, k4 = (li & 15) << 2;
      short4v o;
      #pragma unroll
      for (int j = 0; j < 4; j++) o[j] = sT[k4 + j][nr];
      const int kcol = (k0 + k4) ^ ((nr & 7) << 3);
      *reinterpret_cast<short4v*>(&OUT[(size_t)(n0 + nr) * HID + kcol]) = o;
    }
  } else {
    const int gid = (bid - 1536) * 256 + tid;      // 0..1048575
    const int row = gid >> 7, kc = (gid & 127) << 3;
    const f32x4 a = *reinterpret_cast<const f32x4*>(&X[(size_t)row * HID + kc]);
    const f32x4 b = *reinterpret_cast<const f32x4*>(&X[(size_t)row * HID + kc + 4]);
    short8 s;
    #pragma unroll
    for (int j = 0; j < 4; j++) { s[j] = f2bs(a[j]); s[4 + j] = f2bs(b[j]); }
    const int phys = (kc & ~63) | ((kc & 63) ^ ((row & 7) << 3));
    *reinterpret_cast<short8*>(&XB[(size_t)row * HID + phys]) = s;
  }
}

// ---------------- gated GEMM (m97-geometry): z=0 -> qg, z=1 -> kg -----------
// BM=128 BN=128(dual) BK=64, 256 thr (4 waves, 2x2 of 64x64-dual).
// SINGLE-buffered LDS 48KB -> 2 blocks/CU; 2-barrier loop; compiler lgkm.
__global__ __launch_bounds__(256) void gatedm_kernel(
    const short* __restrict__ XB, const short* __restrict__ WTbase,
    const float* __restrict__ bq, const float* __restrict__ bqr,
    const float* __restrict__ bk, const float* __restrict__ bkr,
    const float* __restrict__ MASK,
    __hip_bfloat16* __restrict__ qg, __hip_bfloat16* __restrict__ kg)
{
  __shared__ short lA[128][64];     // 16 KB
  __shared__ short lB1[128][64];    // 16 KB
  __shared__ short lB2[128][64];    // 16 KB

  const int d = blockIdx.x;
  const int bx = d & 63, byz = d >> 6;
  const int by = byz & 7, z = byz >> 3;

  const short* W1T = WTbase + (size_t)(2 * z) * WT_ELEMS;
  const short* W2T = W1T + WT_ELEMS;
  const float* B1b = z ? bk : bq;
  const float* B2b = z ? bkr : bqr;
  __hip_bfloat16* OUT = z ? kg : qg;

  const int m0 = bx * 128, n0 = by * 128;
  const int tid = threadIdx.x, lane = tid & 63, w = tid >> 6;
  const int wr = (w >> 1) * 64, wc = (w & 1) * 64;
  const int lrow = lane & 15, lkhi = (lane >> 4) << 3;
  const int swz = (lrow & 7) << 3;
  const int srow = lane >> 3, scol = (lane & 7) << 3;

  f32x4 acc1[4][4] = {}, acc2[4][4] = {};
  short8 bf1k[4], bf2k[4], bf1b[4];
  short8 afA0, afA1, afA2, afA3, afB0, afB1, afB2, afB3;

  // staging: per K-tile, 256 thr x 8 issues? No: A 128x64x2B = 16KB / (256x16B)
  // = 4 issues/thread... per-wave-uniform chunks: A: each wave stages 2 chunks
  // of 8 rows? A rows 128 = 16 chunks of 8; 4 waves x 4 = 16. B1/B2: 16 each
  // -> 4 per wave each.
  auto stage = [&](int kt) {
    const int k0 = kt * 64;
    #pragma unroll
    for (int i = 0; i < 4; i++) {
      const int chunk = w * 4 + i;
      gload16(&XB[(size_t)(m0 + chunk * 8 + srow) * HID + k0 + scol],
              &lA[chunk * 8][0]);
    }
    #pragma unroll
    for (int i = 0; i < 4; i++) {
      const int chunk = w * 4 + i;
      gload16(&W1T[(size_t)(n0 + chunk * 8 + srow) * HID + k0 + scol],
              &lB1[chunk * 8][0]);
    }
    #pragma unroll
    for (int i = 0; i < 4; i++) {
      const int chunk = w * 4 + i;
      gload16(&W2T[(size_t)(n0 + chunk * 8 + srow) * HID + k0 + scol],
              &lB2[chunk * 8][0]);
    }
  };
  auto rdA = [&](int m, int kk) -> short8 {
    const int lk = (kk * 32 + lkhi) ^ swz;
    return *reinterpret_cast<const short8*>(&lA[wr + m * 16 + lrow][lk]);
  };

#define RDB1(DST, KK)                                                                 \
  _Pragma("unroll")                                                                   \
  for (int n = 0; n < 4; n++) {                                                       \
    const int lk = ((KK) * 32 + lkhi) ^ swz;                                          \
    DST[n] = *reinterpret_cast<const short8*>(&lB1[wc + n * 16 + lrow][lk]);          \
  }
#define RDB2(DST, KK)                                                                 \
  _Pragma("unroll")                                                                   \
  for (int n = 0; n < 4; n++) {                                                       \
    const int lk = ((KK) * 32 + lkhi) ^ swz;                                          \
    DST[n] = *reinterpret_cast<const short8*>(&lB2[wc + n * 16 + lrow][lk]);          \
  }
#define MMC1(A0, A1, A2, A3, BF)                                          \
  _Pragma("unroll")                                                       \
  for (int n = 0; n < 4; n++) {                                           \
    acc1[0][n] = MFMA16x16(A0, BF[n], acc1[0][n], 0, 0, 0);               \
    acc1[1][n] = MFMA16x16(A1, BF[n], acc1[1][n], 0, 0, 0);               \
    acc1[2][n] = MFMA16x16(A2, BF[n], acc1[2][n], 0, 0, 0);               \
    acc1[3][n] = MFMA16x16(A3, BF[n], acc1[3][n], 0, 0, 0);               \
  }
#define MMC2(A0, A1, A2, A3, BF)                                          \
  _Pragma("unroll")                                                       \
  for (int n = 0; n < 4; n++) {                                           \
    acc2[0][n] = MFMA16x16(A0, BF[n], acc2[0][n], 0, 0, 0);               \
    acc2[1][n] = MFMA16x16(A1, BF[n], acc2[1][n], 0, 0, 0);               \
    acc2[2][n] = MFMA16x16(A2, BF[n], acc2[2][n], 0, 0, 0);               \
    acc2[3][n] = MFMA16x16(A3, BF[n], acc2[3][n], 0, 0, 0);               \
  }

  #pragma unroll 1
  for (int kt = 0; kt < 16; kt++) {
    stage(kt);
    VMWAIT(0);
    BAR();
    afA0 = rdA(0, 0); afA1 = rdA(1, 0); afA2 = rdA(2, 0); afA3 = rdA(3, 0);
    RDB1(bf1k, 0);
    RDB2(bf2k, 0);
    afB0 = rdA(0, 1); afB1 = rdA(1, 1); afB2 = rdA(2, 1); afB3 = rdA(3, 1);
    RDB1(bf1b, 1);
    SCB;
    PRIO1; MMC1(afA0, afA1, afA2, afA3, bf1k) PRIO0;
    PRIO1; MMC2(afA0, afA1, afA2, afA3, bf2k) PRIO0;
    RDB2(bf2k, 1);
    PRIO1; MMC1(afB0, afB1, afB2, afB3, bf1b) PRIO0;
    PRIO1; MMC2(afB0, afB1, afB2, afB3, bf2k) PRIO0;
    BAR();
  }
#undef MMC1
#undef MMC2
#undef RDB1
#undef RDB2

  // epilogue: bias + reasoning-mask blend; C/D: col=lane&15, row=(lane>>4)*4+r
  #pragma unroll
  for (int m = 0; m < 4; m++) {
    const int rbase = m0 + wr + m * 16 + ((lane >> 4) << 2);
    #pragma unroll
    for (int n = 0; n < 4; n++) {
      const int col = n0 + wc + n * 16 + lrow;
      const float bias1 = B1b[col];
      const float bias2 = B2b[col];
      #pragma unroll
      for (int r = 0; r < 4; r++) {
        const int row = rbase + r;
        const float mk = MASK[row];
        const float val = (acc1[m][n][r] + bias1) * (1.f - mk) +
                          (acc2[m][n][r] + bias2) * mk;
        OUT[(size_t)row * HID + col] = __float2bfloat16(val);
      }
    }
  }
}

// ---------------- plain GEMM (single B): V-proj and out-proj ----------------
// BM=256 BN=128 BK=64, 512 thr. Triple-buffered LDS; 1 BAR/tile; vmcnt(6)
// never 0; compiler fine-grained lgkm.
template<bool OUTF32>
__global__ __launch_bounds__(512, 2) void plain8_kernel(
    const short* __restrict__ A, const short* __restrict__ WT,
    const float* __restrict__ BIAS, void* __restrict__ OUTv)
{
  __shared__ short lA[3][256][64];    // 96 KB
  __shared__ short lB[3][128][64];    // 48 KB

  const int d = blockIdx.x;
  const int bx = d & 31, by = d >> 5;

  const int m0 = bx * 256, n0 = by * 128;
  const int tid = threadIdx.x, lane = tid & 63, w = tid >> 6;
  const int wr = (w >> 1) * 64, wc = (w & 1) * 64;
  const int lrow = lane & 15, lkhi = (lane >> 4) << 3;
  const int swz = (lrow & 7) << 3;
  const int srow = lane >> 3, scol = (lane & 7) << 3;

  f32x4 acc[4][4] = {};
  short8 paf[2][4], pbf[2][4];

  auto stTrip = [&](int slot, int kt, int t) {
    const int k0 = kt * 64;
    if (t == 0) {
      #pragma unroll
      for (int i = 0; i < 3; i++) {
        const int chunk = w * 4 + i;
        gload16(&A[(size_t)(m0 + chunk * 8 + srow) * HID + k0 + scol],
                &lA[slot][chunk * 8][0]);
      }
    } else {
      const int chunk = w * 4 + 3;
      gload16(&A[(size_t)(m0 + chunk * 8 + srow) * HID + k0 + scol],
              &lA[slot][chunk * 8][0]);
      #pragma unroll
      for (int i = 0; i < 2; i++) {
        const int bchunk = w * 2 + i;
        gload16(&WT[(size_t)(n0 + bchunk * 8 + srow) * HID + k0 + scol],
                &lB[slot][bchunk * 8][0]);
      }
    }
  };

#define RDP(S, KK)                                                                    \
  _Pragma("unroll")                                                                   \
  for (int m = 0; m < 4; m++) {                                                       \
    const int lk = ((KK) * 32 + lkhi) ^ swz;                                          \
    paf[KK][m] = *reinterpret_cast<const short8*>(&lA[S][wr + m * 16 + lrow][lk]);    \
    pbf[KK][m] = *reinterpret_cast<const short8*>(&lB[S][wc + m * 16 + lrow][lk]);    \
  }
#define PMM16(KK)                                                                     \
  _Pragma("unroll")                                                                   \
  for (int m = 0; m < 4; m++)                                                         \
    _Pragma("unroll")                                                                 \
    for (int n = 0; n < 4; n++)                                                       \
      acc[m][n] = MFMA16x16(paf[KK][m], pbf[KK][n], acc[m][n], 0, 0, 0);

  // prologue: tiles 0,1 into slots 0,1 (12 issues); need tile0 -> vmcnt(6)
  stTrip(0, 0, 0); stTrip(0, 0, 1);
  stTrip(1, 1, 0); stTrip(1, 1, 1);
  VMWAIT(6);
  BAR();

  int s = 0, s2 = 2;
  #pragma unroll 1
  for (int t = 0; t < 16; t++) {
    const int TS = (t < 14) ? t + 2 : 15;   // tail: harmless restage
    RDP(s, 0)
    RDP(s, 1)
    stTrip(s2, TS, 0); stTrip(s2, TS, 1);
    SCB;
    PRIO1; PMM16(0) PRIO0;
    PRIO1; PMM16(1) PRIO0;
    VMWAIT(6);     // guards tile t+1 (leaves t+2's 6 in flight), never 0
    BAR();
    s = (s == 2) ? 0 : s + 1;
    s2 = (s2 == 2) ? 0 : s2 + 1;
  }
  VMWAIT(0);
#undef PMM16
#undef RDP

  #pragma unroll
  for (int m = 0; m < 4; m++) {
    const int rbase = m0 + wr + m * 16 + ((lane >> 4) << 2);
    #pragma unroll
    for (int n = 0; n < 4; n++) {
      const int col = n0 + wc + n * 16 + lrow;
      const float bias = BIAS[col];
      #pragma unroll
      for (int r = 0; r < 4; r++) {
        const float val = acc[m][n][r] + bias;
        const size_t oidx = (size_t)(rbase + r) * HID + col;
        if (OUTF32) ((float*)OUTv)[oidx] = val;
        else ((__hip_bfloat16*)OUTv)[oidx] = __float2bfloat16(val);
      }
    }
  }
}

// ---------------- MFMA per-token 16x16 cross-head attention -----------------
__global__ __launch_bounds__(256) void attn_kernel(
    const __hip_bfloat16* __restrict__ Q, const __hip_bfloat16* __restrict__ K,
    const __hip_bfloat16* __restrict__ V, __hip_bfloat16* __restrict__ O)
{
  __shared__ short sP[4][16][32];   // per-wave P, cols 16..31 stay zero
  const int tid = threadIdx.x, w = tid >> 6, lane = tid & 63;
  const int t = blockIdx.x * 4 + w;
  const int b = t >> 11, s = t & 2047;
  const size_t tb = (size_t)t * HID;
  const short* q = (const short*)Q;
  const short* k = (const short*)K;
  const short* v = (const short*)V;
  const int lrow = lane & 15, lk = lane >> 4;   // lk in 0..3

  *reinterpret_cast<short8*>(&sP[w][lrow][lk * 8]) = short8{0,0,0,0,0,0,0,0};

  f32x4 sc4 = {0.f, 0.f, 0.f, 0.f};
  #pragma unroll
  for (int kk = 0; kk < 2; kk++) {
    const size_t off = tb + (size_t)lrow * 64 + kk * 32 + lk * 8;
    const short8 qf = *reinterpret_cast<const short8*>(&q[off]);
    const short8 kf = *reinterpret_cast<const short8*>(&k[off]);
    sc4 = MFMA16x16(qf, kf, sc4, 0, 0, 0);
  }

  float p[4];
  #pragma unroll
  for (int r = 0; r < 4; r++) {
    const float x = sc4[r] * 0.125f;
    float mx = x;
    mx = fmaxf(mx, __shfl_xor(mx, 1));
    mx = fmaxf(mx, __shfl_xor(mx, 2));
    mx = fmaxf(mx, __shfl_xor(mx, 4));
    mx = fmaxf(mx, __shfl_xor(mx, 8));
    const float e = __expf(x - mx);
    float sm = e;
    sm += __shfl_xor(sm, 1);
    sm += __shfl_xor(sm, 2);
    sm += __shfl_xor(sm, 4);
    sm += __shfl_xor(sm, 8);
    p[r] = e / sm;
  }

  #pragma unroll
  for (int r = 0; r < 4; r++)
    sP[w][lk * 4 + r][lrow] = f2bs(p[r]);
  asm volatile("s_waitcnt lgkmcnt(0)" ::: "memory");
  SCB;

  const short8 af = *reinterpret_cast<const short8*>(&sP[w][lrow][lk * 8]);
  const int row7 = (s >> 4) & 7;
  const size_t obase = ((size_t)b * 2048 + (s >> 4)) * HID + ((size_t)(s & 15) << 6);
  #pragma unroll
  for (int db = 0; db < 4; db++) {
    short8 bf = {0, 0, 0, 0, 0, 0, 0, 0};
    if (lane < 32) {
      #pragma unroll
      for (int j = 0; j < 8; j++)
        bf[j] = v[tb + (size_t)(lk * 8 + j) * 64 + db * 16 + lrow];
    }
    f32x4 o = {0.f, 0.f, 0.f, 0.f};
    o = MFMA16x16(af, bf, o, 0, 0, 0);
    #pragma unroll
    for (int r = 0; r < 4; r++) {
      const int h = lk * 4 + r;
      const int dd = db * 16 + lrow;
      O[obase + (size_t)h * 128 * HID + (dd ^ (row7 << 3))] = __float2bfloat16(o[r]);
    }
  }
}

extern "C" void kernel_launch(void* const* d_in, const int* in_sizes, int n_in,
                              void* d_out, int out_size, void* d_ws, size_t ws_size,
                              hipStream_t stream) {
  (void)in_sizes; (void)n_in; (void)out_size; (void)ws_size;
  const float* x   = (const float*)d_in[0];
  const float* rm  = (const float*)d_in[1];
  const float* Wq  = (const float*)d_in[2];
  const float* bq  = (const float*)d_in[3];
  const float* Wk  = (const float*)d_in[4];
  const float* bk  = (const float*)d_in[5];
  const float* Wv  = (const float*)d_in[6];
  const float* bv  = (const float*)d_in[7];
  const float* Wqr = (const float*)d_in[8];
  const float* bqr = (const float*)d_in[9];
  const float* Wkr = (const float*)d_in[10];
  const float* bkr = (const float*)d_in[11];
  const float* Wo  = (const float*)d_in[12];
  const float* bo  = (const float*)d_in[13];

  char* ws = (char*)d_ws;
  short* wt = (short*)ws;
  __hip_bfloat16* qg = (__hip_bfloat16*)(ws + 12u * 1024 * 1024);
  __hip_bfloat16* vv = (__hip_bfloat16*)(ws + 28u * 1024 * 1024);
  __hip_bfloat16* ar = (__hip_bfloat16*)(ws + 44u * 1024 * 1024);
  short* xb = (short*)d_out;                                        // [0:16M)
  __hip_bfloat16* kg = (__hip_bfloat16*)((char*)d_out + 16u * 1024 * 1024);  // [16:32M)

  prep_kernel<<<dim3(5632), 256, 0, stream>>>(Wq, Wqr, Wk, Wkr, Wv, Wo, x, wt, xb);
  gatedm_kernel<<<dim3(1024), 256, 0, stream>>>(xb, wt, bq, bqr, bk, bkr, rm, qg, kg);
  plain8_kernel<false><<<dim3(256), 512, 0, stream>>>(xb, wt + (size_t)4 * WT_ELEMS, bv, vv);
  attn_kernel<<<dim3(NTOK / 4), 256, 0, stream>>>(qg, kg, vv, ar);
  plain8_kernel<true><<<dim3(256), 512, 0, stream>>>((const short*)ar,
                                                     wt + (size_t)5 * WT_ELEMS, bo, d_out);
}

// Round 16
// 135.202 us; speedup vs baseline: 1.4102x; 1.4102x over previous
//
#include <hip/hip_runtime.h>
#include <hip/hip_bf16.h>

// ReasoningMultiHeadAttention: B=4 S=2048 HID=1024 NH=16 DH=64. All I/O fp32.
// prep: 6x W -> bf16 W^T pre-swizzled (wt) ; x -> bf16 xb pre-swizzled (d_out lo)
// gated3 (R16): dual-B BM=256 BK=64, 512 thr; A TRIPLE-buffered, B1/B2 DOUBLE
//   -> 160KB LDS exactly; per-tile VMWAIT(4) NEVER 0 (plain8's amortization,
//   which is why plain8 hits 1012 TF vs gated's 529 with full drains).
// plain8<bf16>: xb @ WvT + bv -> vv ; triple-buffer, 1 BAR/tile, vmcnt(6)
// attn: MFMA per-token cross-head attention (R14)
// plain8<f32>: ar @ WoT + bo -> d_out
// ws: [0:12M wt][12:28M qg][28:44M vv][44:60M ar]; d_out scratch: xb | kg.

typedef __attribute__((ext_vector_type(8))) short short8;
typedef __attribute__((ext_vector_type(4))) short short4v;
typedef __attribute__((ext_vector_type(4))) float f32x4;

#define HID 1024
#define NTOK 8192
#define WT_ELEMS (1024 * 1024)

__device__ __forceinline__ short f2bs(float f) {
  __hip_bfloat16 h = __float2bfloat16(f);
  return *reinterpret_cast<short*>(&h);
}
__device__ __forceinline__ float bs2f(short s) {
  __hip_bfloat16 h;
  *reinterpret_cast<short*>(&h) = s;
  return __bfloat162float(h);
}
__device__ __forceinline__ void gload16(const void* g, void* l) {
  __builtin_amdgcn_global_load_lds(
      (const __attribute__((address_space(1))) void*)g,
      (__attribute__((address_space(3))) void*)l, 16, 0, 0);
}

#define BAR() asm volatile("s_barrier" ::: "memory")
#define VMWAIT(N) asm volatile("s_waitcnt vmcnt(" #N ")" ::: "memory")
#define SCB __builtin_amdgcn_sched_barrier(0)
#define PRIO1 __builtin_amdgcn_s_setprio(1)
#define PRIO0 __builtin_amdgcn_s_setprio(0)
#define MFMA16x16 __builtin_amdgcn_mfma_f32_16x16x32_bf16

// ---------------- prep: W transposes (z<6) + x fp32->bf16 convert ----------
__global__ __launch_bounds__(256) void prep_kernel(
    const float* __restrict__ W0, const float* __restrict__ W1,
    const float* __restrict__ W2, const float* __restrict__ W3,
    const float* __restrict__ W4, const float* __restrict__ W5,
    const float* __restrict__ X, short* __restrict__ WT, short* __restrict__ XB)
{
  __shared__ short sT[64][68];
  const int bid = blockIdx.x, tid = threadIdx.x;
  if (bid < 1536) {
    const int z = bid >> 8, rem = bid & 255;
    const float* W = z == 0 ? W0 : z == 1 ? W1 : z == 2 ? W2 : z == 3 ? W3
                   : z == 4 ? W4 : W5;
    short* OUT = WT + (size_t)z * WT_ELEMS;
    const int k0 = (rem & 15) * 64, n0 = (rem >> 4) * 64;
    #pragma unroll
    for (int i = 0; i < 4; i++) {
      const int li = tid + i * 256;
      const int kr = li >> 4, c4 = (li & 15) << 2;
      const f32x4 wv = *reinterpret_cast<const f32x4*>(&W[(size_t)(k0 + kr) * HID + n0 + c4]);
      short4v s4;
      #pragma unroll
      for (int j = 0; j < 4; j++) s4[j] = f2bs(wv[j]);
      *reinterpret_cast<short4v*>(&sT[kr][c4]) = s4;
    }
    __syncthreads();
    #pragma unroll
    for (int i = 0; i < 4; i++) {
      const int li = tid + i * 256;
      const int nr = li >> 4, k4 = (li & 15) << 2;
      short4v o;
      #pragma unroll
      for (int j = 0; j < 4; j++) o[j] = sT[k4 + j][nr];
      const int kcol = (k0 + k4) ^ ((nr & 7) << 3);
      *reinterpret_cast<short4v*>(&OUT[(size_t)(n0 + nr) * HID + kcol]) = o;
    }
  } else {
    const int gid = (bid - 1536) * 256 + tid;      // 0..1048575
    const int row = gid >> 7, kc = (gid & 127) << 3;
    const f32x4 a = *reinterpret_cast<const f32x4*>(&X[(size_t)row * HID + kc]);
    const f32x4 b = *reinterpret_cast<const f32x4*>(&X[(size_t)row * HID + kc + 4]);
    short8 s;
    #pragma unroll
    for (int j = 0; j < 4; j++) { s[j] = f2bs(a[j]); s[4 + j] = f2bs(b[j]); }
    const int phys = (kc & ~63) | ((kc & 63) ^ ((row & 7) << 3));
    *reinterpret_cast<short8*>(&XB[(size_t)row * HID + phys]) = s;
  }
}

// ---------------- gated GEMM (A-triple / B-double): z=0 -> qg, z=1 -> kg ----
// BM=256 BN=128 BK=64, 512 thr (8 waves), dual-B, linear block map.
// Per tile: 24 ds_reads + 8 stage-issues; 4 MFMA clusters (compiler lgkm);
// VMWAIT(4) never 0; single BAR.
__global__ __launch_bounds__(512, 2) void gated3_kernel(
    const short* __restrict__ XB, const short* __restrict__ WTbase,
    const float* __restrict__ bq, const float* __restrict__ bqr,
    const float* __restrict__ bk, const float* __restrict__ bkr,
    const float* __restrict__ MASK,
    __hip_bfloat16* __restrict__ qg, __hip_bfloat16* __restrict__ kg)
{
  __shared__ short lA[3][256][64];    // 96 KB
  __shared__ short lB1[2][128][64];   // 32 KB
  __shared__ short lB2[2][128][64];   // 32 KB  -> 160 KB total

  const int d = blockIdx.x;
  const int bx = d & 31, byz = d >> 5;
  const int by = byz & 7, z = byz >> 3;

  const short* W1T = WTbase + (size_t)(2 * z) * WT_ELEMS;
  const short* W2T = W1T + WT_ELEMS;
  const float* B1b = z ? bk : bq;
  const float* B2b = z ? bkr : bqr;
  __hip_bfloat16* OUT = z ? kg : qg;

  const int m0 = bx * 256, n0 = by * 128;
  const int tid = threadIdx.x, lane = tid & 63, w = tid >> 6;
  const int wr = (w >> 1) * 64, wc = (w & 1) * 64;
  const int lrow = lane & 15, lkhi = (lane >> 4) << 3;
  const int swz = (lrow & 7) << 3;
  const int srow = lane >> 3, scol = (lane & 7) << 3;

  f32x4 acc1[4][4] = {}, acc2[4][4] = {};
  short8 bf1k[4], bf2k[4], bf1b[4];
  short8 afA0, afA1, afA2, afA3, afB0, afB1, afB2, afB3;

  auto stA4 = [&](int slot, int kt) {           // 4 A-issues
    const int k0 = kt * 64;
    #pragma unroll
    for (int i = 0; i < 4; i++) {
      const int chunk = w * 4 + i;
      gload16(&XB[(size_t)(m0 + chunk * 8 + srow) * HID + k0 + scol],
              &lA[slot][chunk * 8][0]);
    }
  };
  auto stB1s = [&](int slot, int kt) {          // 2 B1-issues
    const int k0 = kt * 64;
    #pragma unroll
    for (int i = 0; i < 2; i++) {
      const int chunk = w * 2 + i;
      gload16(&W1T[(size_t)(n0 + chunk * 8 + srow) * HID + k0 + scol],
              &lB1[slot][chunk * 8][0]);
    }
  };
  auto stB2s = [&](int slot, int kt) {          // 2 B2-issues
    const int k0 = kt * 64;
    #pragma unroll
    for (int i = 0; i < 2; i++) {
      const int chunk = w * 2 + i;
      gload16(&W2T[(size_t)(n0 + chunk * 8 + srow) * HID + k0 + scol],
              &lB2[slot][chunk * 8][0]);
    }
  };
  auto rdA = [&](int s, int m, int kk) -> short8 {
    const int lk = (kk * 32 + lkhi) ^ swz;
    return *reinterpret_cast<const short8*>(&lA[s][wr + m * 16 + lrow][lk]);
  };

#define RDB1(DST, S, KK)                                                              \
  _Pragma("unroll")                                                                   \
  for (int n = 0; n < 4; n++) {                                                       \
    const int lk = ((KK) * 32 + lkhi) ^ swz;                                          \
    DST[n] = *reinterpret_cast<const short8*>(&lB1[S][wc + n * 16 + lrow][lk]);       \
  }
#define RDB2(DST, S, KK)                                                              \
  _Pragma("unroll")                                                                   \
  for (int n = 0; n < 4; n++) {                                                       \
    const int lk = ((KK) * 32 + lkhi) ^ swz;                                          \
    DST[n] = *reinterpret_cast<const short8*>(&lB2[S][wc + n * 16 + lrow][lk]);       \
  }
#define MMC1(A0, A1, A2, A3, BF)                                          \
  _Pragma("unroll")                                                       \
  for (int n = 0; n < 4; n++) {                                           \
    acc1[0][n] = MFMA16x16(A0, BF[n], acc1[0][n], 0, 0, 0);               \
    acc1[1][n] = MFMA16x16(A1, BF[n], acc1[1][n], 0, 0, 0);               \
    acc1[2][n] = MFMA16x16(A2, BF[n], acc1[2][n], 0, 0, 0);               \
    acc1[3][n] = MFMA16x16(A3, BF[n], acc1[3][n], 0, 0, 0);               \
  }
#define MMC2(A0, A1, A2, A3, BF)                                          \
  _Pragma("unroll")                                                       \
  for (int n = 0; n < 4; n++) {                                           \
    acc2[0][n] = MFMA16x16(A0, BF[n], acc2[0][n], 0, 0, 0);               \
    acc2[1][n] = MFMA16x16(A1, BF[n], acc2[1][n], 0, 0, 0);               \
    acc2[2][n] = MFMA16x16(A2, BF[n], acc2[2][n], 0, 0, 0);               \
    acc2[3][n] = MFMA16x16(A3, BF[n], acc2[3][n], 0, 0, 0);               \
  }

  // prologue: B1(0),B2(0) -> Bslot0; A(0) -> Aslot0; A(1) -> Aslot1.
  // 12 issues; VMWAIT(4) drains B(0)+A(0), leaves A(1) in flight.
  stB1s(0, 0); stB2s(0, 0); stA4(0, 0); stA4(1, 1);
  VMWAIT(4);
  BAR();

  #pragma unroll 1
  for (int t = 0; t < 16; t++) {
    const int sa = t % 3, sb = t & 1;
    const int ktB = (t < 15) ? t + 1 : 15;     // B(t+1) -> slot (t+1)&1 (!= sb)
    const int ktA = (t < 14) ? t + 2 : 15;     // A(t+2) -> slot (t+2)%3 (safe)
    // reads (24) — compiler inserts fine-grained lgkm before each MFMA use
    afA0 = rdA(sa, 0, 0); afA1 = rdA(sa, 1, 0);
    afA2 = rdA(sa, 2, 0); afA3 = rdA(sa, 3, 0);
    RDB1(bf1k, sb, 0);
    RDB2(bf2k, sb, 0);
    afB0 = rdA(sa, 0, 1); afB1 = rdA(sa, 1, 1);
    afB2 = rdA(sa, 2, 1); afB3 = rdA(sa, 3, 1);
    RDB1(bf1b, sb, 1);
    // stage next (8 issues): B(t+1) first, then A(t+2)
    stB1s((t + 1) & 1, ktB); stB2s((t + 1) & 1, ktB);
    stA4((t + 2) % 3, ktA);
    SCB;
    PRIO1; MMC1(afA0, afA1, afA2, afA3, bf1k) PRIO0;
    PRIO1; MMC2(afA0, afA1, afA2, afA3, bf2k) PRIO0;
    RDB2(bf2k, sb, 1);
    PRIO1; MMC1(afB0, afB1, afB2, afB3, bf1b) PRIO0;
    PRIO1; MMC2(afB0, afB1, afB2, afB3, bf2k) PRIO0;
    VMWAIT(4);       // drains B(t+1)+A(t+1); leaves A(t+2)'s 4 — never 0
    BAR();
  }
  VMWAIT(0);
#undef MMC1
#undef MMC2
#undef RDB1
#undef RDB2

  // epilogue: bias + reasoning-mask blend; C/D: col=lane&15, row=(lane>>4)*4+r
  #pragma unroll
  for (int m = 0; m < 4; m++) {
    const int rbase = m0 + wr + m * 16 + ((lane >> 4) << 2);
    #pragma unroll
    for (int n = 0; n < 4; n++) {
      const int col = n0 + wc + n * 16 + lrow;
      const float bias1 = B1b[col];
      const float bias2 = B2b[col];
      #pragma unroll
      for (int r = 0; r < 4; r++) {
        const int row = rbase + r;
        const float mk = MASK[row];
        const float val = (acc1[m][n][r] + bias1) * (1.f - mk) +
                          (acc2[m][n][r] + bias2) * mk;
        OUT[(size_t)row * HID + col] = __float2bfloat16(val);
      }
    }
  }
}

// ---------------- plain GEMM (single B): V-proj and out-proj ----------------
// BM=256 BN=128 BK=64, 512 thr. Triple-buffered LDS; 1 BAR/tile; vmcnt(6)
// never 0; compiler fine-grained lgkm.
template<bool OUTF32>
__global__ __launch_bounds__(512, 2) void plain8_kernel(
    const short* __restrict__ A, const short* __restrict__ WT,
    const float* __restrict__ BIAS, void* __restrict__ OUTv)
{
  __shared__ short lA[3][256][64];    // 96 KB
  __shared__ short lB[3][128][64];    // 48 KB

  const int d = blockIdx.x;
  const int bx = d & 31, by = d >> 5;

  const int m0 = bx * 256, n0 = by * 128;
  const int tid = threadIdx.x, lane = tid & 63, w = tid >> 6;
  const int wr = (w >> 1) * 64, wc = (w & 1) * 64;
  const int lrow = lane & 15, lkhi = (lane >> 4) << 3;
  const int swz = (lrow & 7) << 3;
  const int srow = lane >> 3, scol = (lane & 7) << 3;

  f32x4 acc[4][4] = {};
  short8 paf[2][4], pbf[2][4];

  auto stTrip = [&](int slot, int kt, int t) {
    const int k0 = kt * 64;
    if (t == 0) {
      #pragma unroll
      for (int i = 0; i < 3; i++) {
        const int chunk = w * 4 + i;
        gload16(&A[(size_t)(m0 + chunk * 8 + srow) * HID + k0 + scol],
                &lA[slot][chunk * 8][0]);
      }
    } else {
      const int chunk = w * 4 + 3;
      gload16(&A[(size_t)(m0 + chunk * 8 + srow) * HID + k0 + scol],
              &lA[slot][chunk * 8][0]);
      #pragma unroll
      for (int i = 0; i < 2; i++) {
        const int bchunk = w * 2 + i;
        gload16(&WT[(size_t)(n0 + bchunk * 8 + srow) * HID + k0 + scol],
                &lB[slot][bchunk * 8][0]);
      }
    }
  };

#define RDP(S, KK)                                                                    \
  _Pragma("unroll")                                                                   \
  for (int m = 0; m < 4; m++) {                                                       \
    const int lk = ((KK) * 32 + lkhi) ^ swz;                                          \
    paf[KK][m] = *reinterpret_cast<const short8*>(&lA[S][wr + m * 16 + lrow][lk]);    \
    pbf[KK][m] = *reinterpret_cast<const short8*>(&lB[S][wc + m * 16 + lrow][lk]);    \
  }
#define PMM16(KK)                                                                     \
  _Pragma("unroll")                                                                   \
  for (int m = 0; m < 4; m++)                                                         \
    _Pragma("unroll")                                                                 \
    for (int n = 0; n < 4; n++)                                                       \
      acc[m][n] = MFMA16x16(paf[KK][m], pbf[KK][n], acc[m][n], 0, 0, 0);

  // prologue: tiles 0,1 into slots 0,1 (12 issues); need tile0 -> vmcnt(6)
  stTrip(0, 0, 0); stTrip(0, 0, 1);
  stTrip(1, 1, 0); stTrip(1, 1, 1);
  VMWAIT(6);
  BAR();

  int s = 0, s2 = 2;
  #pragma unroll 1
  for (int t = 0; t < 16; t++) {
    const int TS = (t < 14) ? t + 2 : 15;   // tail: harmless restage
    RDP(s, 0)
    RDP(s, 1)
    stTrip(s2, TS, 0); stTrip(s2, TS, 1);
    SCB;
    PRIO1; PMM16(0) PRIO0;
    PRIO1; PMM16(1) PRIO0;
    VMWAIT(6);     // guards tile t+1 (leaves t+2's 6 in flight), never 0
    BAR();
    s = (s == 2) ? 0 : s + 1;
    s2 = (s2 == 2) ? 0 : s2 + 1;
  }
  VMWAIT(0);
#undef PMM16
#undef RDP

  #pragma unroll
  for (int m = 0; m < 4; m++) {
    const int rbase = m0 + wr + m * 16 + ((lane >> 4) << 2);
    #pragma unroll
    for (int n = 0; n < 4; n++) {
      const int col = n0 + wc + n * 16 + lrow;
      const float bias = BIAS[col];
      #pragma unroll
      for (int r = 0; r < 4; r++) {
        const float val = acc[m][n][r] + bias;
        const size_t oidx = (size_t)(rbase + r) * HID + col;
        if (OUTF32) ((float*)OUTv)[oidx] = val;
        else ((__hip_bfloat16*)OUTv)[oidx] = __float2bfloat16(val);
      }
    }
  }
}

// ---------------- MFMA per-token 16x16 cross-head attention -----------------
__global__ __launch_bounds__(256) void attn_kernel(
    const __hip_bfloat16* __restrict__ Q, const __hip_bfloat16* __restrict__ K,
    const __hip_bfloat16* __restrict__ V, __hip_bfloat16* __restrict__ O)
{
  __shared__ short sP[4][16][32];   // per-wave P, cols 16..31 stay zero
  const int tid = threadIdx.x, w = tid >> 6, lane = tid & 63;
  const int t = blockIdx.x * 4 + w;
  const int b = t >> 11, s = t & 2047;
  const size_t tb = (size_t)t * HID;
  const short* q = (const short*)Q;
  const short* k = (const short*)K;
  const short* v = (const short*)V;
  const int lrow = lane & 15, lk = lane >> 4;   // lk in 0..3

  *reinterpret_cast<short8*>(&sP[w][lrow][lk * 8]) = short8{0,0,0,0,0,0,0,0};

  f32x4 sc4 = {0.f, 0.f, 0.f, 0.f};
  #pragma unroll
  for (int kk = 0; kk < 2; kk++) {
    const size_t off = tb + (size_t)lrow * 64 + kk * 32 + lk * 8;
    const short8 qf = *reinterpret_cast<const short8*>(&q[off]);
    const short8 kf = *reinterpret_cast<const short8*>(&k[off]);
    sc4 = MFMA16x16(qf, kf, sc4, 0, 0, 0);
  }

  float p[4];
  #pragma unroll
  for (int r = 0; r < 4; r++) {
    const float x = sc4[r] * 0.125f;
    float mx = x;
    mx = fmaxf(mx, __shfl_xor(mx, 1));
    mx = fmaxf(mx, __shfl_xor(mx, 2));
    mx = fmaxf(mx, __shfl_xor(mx, 4));
    mx = fmaxf(mx, __shfl_xor(mx, 8));
    const float e = __expf(x - mx);
    float sm = e;
    sm += __shfl_xor(sm, 1);
    sm += __shfl_xor(sm, 2);
    sm += __shfl_xor(sm, 4);
    sm += __shfl_xor(sm, 8);
    p[r] = e / sm;
  }

  #pragma unroll
  for (int r = 0; r < 4; r++)
    sP[w][lk * 4 + r][lrow] = f2bs(p[r]);
  asm volatile("s_waitcnt lgkmcnt(0)" ::: "memory");
  SCB;

  const short8 af = *reinterpret_cast<const short8*>(&sP[w][lrow][lk * 8]);
  const int row7 = (s >> 4) & 7;
  const size_t obase = ((size_t)b * 2048 + (s >> 4)) * HID + ((size_t)(s & 15) << 6);
  #pragma unroll
  for (int db = 0; db < 4; db++) {
    short8 bf = {0, 0, 0, 0, 0, 0, 0, 0};
    if (lane < 32) {
      #pragma unroll
      for (int j = 0; j < 8; j++)
        bf[j] = v[tb + (size_t)(lk * 8 + j) * 64 + db * 16 + lrow];
    }
    f32x4 o = {0.f, 0.f, 0.f, 0.f};
    o = MFMA16x16(af, bf, o, 0, 0, 0);
    #pragma unroll
    for (int r = 0; r < 4; r++) {
      const int h = lk * 4 + r;
      const int dd = db * 16 + lrow;
      O[obase + (size_t)h * 128 * HID + (dd ^ (row7 << 3))] = __float2bfloat16(o[r]);
    }
  }
}

extern "C" void kernel_launch(void* const* d_in, const int* in_sizes, int n_in,
                              void* d_out, int out_size, void* d_ws, size_t ws_size,
                              hipStream_t stream) {
  (void)in_sizes; (void)n_in; (void)out_size; (void)ws_size;
  const float* x   = (const float*)d_in[0];
  const float* rm  = (const float*)d_in[1];
  const float* Wq  = (const float*)d_in[2];
  const float* bq  = (const float*)d_in[3];
  const float* Wk  = (const float*)d_in[4];
  const float* bk  = (const float*)d_in[5];
  const float* Wv  = (const float*)d_in[6];
  const float* bv  = (const float*)d_in[7];
  const float* Wqr = (const float*)d_in[8];
  const float* bqr = (const float*)d_in[9];
  const float* Wkr = (const float*)d_in[10];
  const float* bkr = (const float*)d_in[11];
  const float* Wo  = (const float*)d_in[12];
  const float* bo  = (const float*)d_in[13];

  char* ws = (char*)d_ws;
  short* wt = (short*)ws;
  __hip_bfloat16* qg = (__hip_bfloat16*)(ws + 12u * 1024 * 1024);
  __hip_bfloat16* vv = (__hip_bfloat16*)(ws + 28u * 1024 * 1024);
  __hip_bfloat16* ar = (__hip_bfloat16*)(ws + 44u * 1024 * 1024);
  short* xb = (short*)d_out;                                        // [0:16M)
  __hip_bfloat16* kg = (__hip_bfloat16*)((char*)d_out + 16u * 1024 * 1024);  // [16:32M)

  prep_kernel<<<dim3(5632), 256, 0, stream>>>(Wq, Wqr, Wk, Wkr, Wv, Wo, x, wt, xb);
  gated3_kernel<<<dim3(512), 512, 0, stream>>>(xb, wt, bq, bqr, bk, bkr, rm, qg, kg);
  plain8_kernel<false><<<dim3(256), 512, 0, stream>>>(xb, wt + (size_t)4 * WT_ELEMS, bv, vv);
  attn_kernel<<<dim3(NTOK / 4), 256, 0, stream>>>(qg, kg, vv, ar);
  plain8_kernel<true><<<dim3(256), 512, 0, stream>>>((const short*)ar,
                                                     wt + (size_t)5 * WT_ELEMS, bo, d_out);
}